// Round 5
// baseline (345.360 us; speedup 1.0000x reference)
//
#include <hip/hip_runtime.h>
#include <hip/hip_bf16.h>
#include <stdint.h>

#define B_ 8
#define N_ 2048
#define F_ 64
#define FH_ 64
#define H_ 4
#define C_ (H_*FH_)
#define LOG2E 1.44269504088896340736f

typedef short short8 __attribute__((ext_vector_type(8)));   // 8 bf16 raw bits (4 VGPRs)
typedef float f32x4 __attribute__((ext_vector_type(4)));

// float -> bf16 raw bits (RNE)
__device__ __forceinline__ short f2bf(float f) {
    __hip_bfloat16 h = __float2bfloat16(f);
    return __builtin_bit_cast(short, h);
}

// ---------------- K0: WT[h][o][f] = bf16(W[h][f][o]) ----------------
__global__ __launch_bounds__(256) void k0_wt(const float* __restrict__ W,
                                             __hip_bfloat16* __restrict__ WT) {
    int idx = blockIdx.x * 256 + threadIdx.x;   // 16384 elems total
    int h = idx >> 12, rem = idx & 4095, o = rem >> 6, f = rem & 63;
    WT[idx] = __float2bfloat16(W[(h * F_ + f) * FH_ + o]);
}

// ---------------- K1: featsT = (X@W)^T via MFMA, fused ss/sn epilogue ----------------
// featsT[b][h][o][n]; ss/sn[b][h][n] = log2(e) * feats[b,h,n,:] . a_{self,neigh}[h]
__global__ __launch_bounds__(256) void k1_feats(const float* __restrict__ X,
                                                const __hip_bfloat16* __restrict__ WT,
                                                const float* __restrict__ a_self,
                                                const float* __restrict__ a_neigh,
                                                __hip_bfloat16* __restrict__ featsT,
                                                float* __restrict__ ss,
                                                float* __restrict__ sn) {
    __shared__ float a_lds[2][FH_];
    const int nb = blockIdx.x, h = blockIdx.y, b = blockIdx.z;
    const int tid = threadIdx.x;
    if (tid < 64)       a_lds[0][tid] = a_self[h * FH_ + tid];
    else if (tid < 128) a_lds[1][tid - 64] = a_neigh[h * FH_ + tid - 64];
    __syncthreads();

    const int wave = tid >> 6, lane = tid & 63;
    const int m = lane & 15, q = lane >> 4;
    const int n = nb * 64 + wave * 16 + m;      // B-frag column (node index)
    f32x4 acc[4] = {};
#pragma unroll
    for (int ks = 0; ks < 2; ++ks) {            // K = F = 64, two steps of 32
        const float* xp = X + ((size_t)(b * N_ + n)) * F_ + ks * 32 + q * 8;
        float4 x0 = *(const float4*)xp;
        float4 x1 = *(const float4*)(xp + 4);
        short8 bfrag;
        bfrag[0] = f2bf(x0.x); bfrag[1] = f2bf(x0.y);
        bfrag[2] = f2bf(x0.z); bfrag[3] = f2bf(x0.w);
        bfrag[4] = f2bf(x1.x); bfrag[5] = f2bf(x1.y);
        bfrag[6] = f2bf(x1.z); bfrag[7] = f2bf(x1.w);
#pragma unroll
        for (int ot = 0; ot < 4; ++ot) {        // 64 output features = 4 row tiles
            short8 afrag = *(const short8*)(WT + ((size_t)(h * FH_ + ot * 16 + m)) * F_ + ks * 32 + q * 8);
            acc[ot] = __builtin_amdgcn_mfma_f32_16x16x32_bf16(afrag, bfrag, acc[ot], 0, 0, 0);
        }
    }
    float ssv = 0.f, snv = 0.f;
#pragma unroll
    for (int ot = 0; ot < 4; ++ot) {
#pragma unroll
        for (int r = 0; r < 4; ++r) {
            int orow = ot * 16 + q * 4 + r;     // C: row=(lane>>4)*4+r, col=lane&15
            float v = acc[ot][r];
            featsT[((size_t)(b * H_ + h) * FH_ + orow) * N_ + n] = __float2bfloat16(v);
            ssv += v * a_lds[0][orow];
            snv += v * a_lds[1][orow];
        }
    }
    // reduce over the 4 q-groups that share column n
    ssv += __shfl_xor(ssv, 16); ssv += __shfl_xor(ssv, 32);
    snv += __shfl_xor(snv, 16); snv += __shfl_xor(snv, 32);
    if (lane < 16) {
        ss[((size_t)(b * H_ + h)) * N_ + n] = ssv * LOG2E;
        sn[((size_t)(b * H_ + h)) * N_ + n] = snv * LOG2E;
    }
}

// ---------------- K3: fused mask+softmax(no-max)+PV MFMA + epilogue ----------------
// grid (N/64, H, B); block = 4 waves, one head, 64 rows; wave handles 16 rows.
// exp(leaky(ss_i+sn_j)) = (hi>1 ? hi : lo), hi = 2^ss_i * 2^sn_j, lo = 2^0.2ss_i * 2^0.2sn_j
__global__ __launch_bounds__(256) void k3_attn(const float* __restrict__ A,
                                               const __hip_bfloat16* __restrict__ featsT,
                                               const float* __restrict__ ss,
                                               const float* __restrict__ sn,
                                               const float* __restrict__ bias,
                                               float* __restrict__ out) {
    __shared__ float e1_lds[N_];                // 2^sn_j
    __shared__ float e2_lds[N_];                // 2^(0.2 sn_j)
    const int tile = blockIdx.x, h = blockIdx.y, b = blockIdx.z;
    const int tid = threadIdx.x, wave = tid >> 6, lane = tid & 63;
    const int m = lane & 15, q = lane >> 4;

    {   // stage per-column exp tables for this head
        const float4* snrow = (const float4*)(sn + ((size_t)(b * H_ + h)) * N_);
        float4* e1v = (float4*)e1_lds;
        float4* e2v = (float4*)e2_lds;
#pragma unroll
        for (int i = 0; i < 2; ++i) {
            int idx = tid + i * 256;            // 0..511 float4 slots
            float4 v = snrow[idx];
            float4 u1, u2;
            u1.x = exp2f(v.x); u1.y = exp2f(v.y); u1.z = exp2f(v.z); u1.w = exp2f(v.w);
            u2.x = exp2f(0.2f * v.x); u2.y = exp2f(0.2f * v.y);
            u2.z = exp2f(0.2f * v.z); u2.w = exp2f(0.2f * v.w);
            e1v[idx] = u1; e2v[idx] = u2;
        }
    }
    const int rowbase = tile * 64 + wave * 16;
    const float ss0 = ss[((size_t)(b * H_ + h)) * N_ + rowbase + m];
    const float e1i = exp2f(ss0), e2i = exp2f(0.2f * ss0);
    __syncthreads();

    const float* arow = A + ((size_t)(b * N_ + rowbase + m)) * N_ + q * 8;
    const __hip_bfloat16* fb = featsT + (((size_t)(b * H_ + h)) * FH_ + m) * N_ + q * 8;
    const float* p1 = e1_lds + q * 8;
    const float* p2 = e2_lds + q * 8;

    f32x4 acc[4] = {};
    f32x4 accl = {};                            // row sums via ones-MFMA
    short8 ones;
#pragma unroll
    for (int s = 0; s < 8; ++s) ones[s] = (short)0x3F80;   // bf16 1.0

#pragma unroll 2
    for (int jb = 0; jb < N_; jb += 32) {
        float4 ea0 = *(const float4*)(p1 + jb);
        float4 ea1 = *(const float4*)(p1 + jb + 4);
        float4 eb0 = *(const float4*)(p2 + jb);
        float4 eb1 = *(const float4*)(p2 + jb + 4);
        float4 m0  = *(const float4*)(arow + jb);
        float4 m1  = *(const float4*)(arow + jb + 4);
        float e1a[8] = {ea0.x, ea0.y, ea0.z, ea0.w, ea1.x, ea1.y, ea1.z, ea1.w};
        float e2a[8] = {eb0.x, eb0.y, eb0.z, eb0.w, eb1.x, eb1.y, eb1.z, eb1.w};
        float mk[8]  = {m0.x, m0.y, m0.z, m0.w, m1.x, m1.y, m1.z, m1.w};
        short8 p;
#pragma unroll
        for (int s = 0; s < 8; ++s) {
            float hi = e1i * e1a[s];
            float lo = e2i * e2a[s];
            float v = (hi > 1.0f) ? hi : lo;    // = exp2(leaky(s)), sign test exact
            p[s] = f2bf(mk[s] * v);             // adjacency mask in {0,1}
        }
#pragma unroll
        for (int ct = 0; ct < 4; ++ct) {
            short8 fv = *(const short8*)(fb + (size_t)(ct * 16) * N_ + jb);
            acc[ct] = __builtin_amdgcn_mfma_f32_16x16x32_bf16(p, fv, acc[ct], 0, 0, 0);
        }
        accl = __builtin_amdgcn_mfma_f32_16x16x32_bf16(p, ones, accl, 0, 0, 0);
    }

    float bc[4];
#pragma unroll
    for (int ct = 0; ct < 4; ++ct) bc[ct] = bias[h * FH_ + ct * 16 + m];

#pragma unroll
    for (int r = 0; r < 4; ++r) {
        float inv = 1.0f / accl[r];             // row sum for row q*4+r (all cols equal)
        int gr = rowbase + q * 4 + r;
#pragma unroll
        for (int ct = 0; ct < 4; ++ct) {
            float v = acc[ct][r] * inv + bc[ct];
            out[((size_t)(b * N_) + gr) * C_ + h * FH_ + ct * 16 + m] = fmaxf(v, 0.0f);
        }
    }
}

extern "C" void kernel_launch(void* const* d_in, const int* in_sizes, int n_in,
                              void* d_out, int out_size, void* d_ws, size_t ws_size,
                              hipStream_t stream) {
    const float* X       = (const float*)d_in[0];
    const float* A       = (const float*)d_in[1];
    const float* W       = (const float*)d_in[2];
    const float* bias    = (const float*)d_in[3];
    const float* a_self  = (const float*)d_in[4];
    const float* a_neigh = (const float*)d_in[5];
    float* out = (float*)d_out;   // reference output dtype is float32

    char* ws = (char*)d_ws;
    __hip_bfloat16* featsT = (__hip_bfloat16*)(ws);             // 8 MB   [B][H][FH][N]
    __hip_bfloat16* WT     = (__hip_bfloat16*)(ws + 8388608);   // 32 KB  [H][FH][F]
    float* ss              = (float*)(ws + 8421376);            // 256 KB [B][H][N]
    float* sn              = (float*)(ws + 8683520);            // 256 KB [B][H][N]

    k0_wt    <<<64, 256, 0, stream>>>(W, WT);
    k1_feats <<<dim3(N_ / 64, H_, B_), 256, 0, stream>>>(X, WT, a_self, a_neigh, featsT, ss, sn);
    k3_attn  <<<dim3(N_ / 64, H_, B_), 256, 0, stream>>>(A, featsT, ss, sn, bias, out);
}

// Round 6
// 299.684 us; speedup vs baseline: 1.1524x; 1.1524x over previous
//
#include <hip/hip_runtime.h>
#include <hip/hip_bf16.h>
#include <stdint.h>

#define B_ 8
#define N_ 2048
#define F_ 64
#define FH_ 64
#define H_ 4
#define C_ (H_*FH_)
#define LOG2E 1.44269504088896340736f

typedef short short8 __attribute__((ext_vector_type(8)));   // 8 bf16 raw bits (4 VGPRs)
typedef float f32x4 __attribute__((ext_vector_type(4)));

// float -> bf16 raw bits (RNE)
__device__ __forceinline__ short f2bf(float f) {
    __hip_bfloat16 h = __float2bfloat16(f);
    return __builtin_bit_cast(short, h);
}

// ---------------- K0: WT[h][o][f] = bf16(W[h][f][o]) ----------------
__global__ __launch_bounds__(256) void k0_wt(const float* __restrict__ W,
                                             __hip_bfloat16* __restrict__ WT) {
    int idx = blockIdx.x * 256 + threadIdx.x;   // 16384 elems total
    int h = idx >> 12, rem = idx & 4095, o = rem >> 6, f = rem & 63;
    WT[idx] = __float2bfloat16(W[(h * F_ + f) * FH_ + o]);
}

// ---------------- K1: featsT = (X@W)^T via MFMA, fused ss/sn epilogue ----------------
// featsT[b][h][o][n]; ss/sn[b][h][n] = log2(e) * feats[b,h,n,:] . a_{self,neigh}[h]
__global__ __launch_bounds__(256) void k1_feats(const float* __restrict__ X,
                                                const __hip_bfloat16* __restrict__ WT,
                                                const float* __restrict__ a_self,
                                                const float* __restrict__ a_neigh,
                                                __hip_bfloat16* __restrict__ featsT,
                                                float* __restrict__ ss,
                                                float* __restrict__ sn) {
    __shared__ float a_lds[2][FH_];
    __shared__ __hip_bfloat16 c_lds[FH_ * 72];  // padded leading dim 72 vs 64
    const int nb = blockIdx.x, h = blockIdx.y, b = blockIdx.z;
    const int tid = threadIdx.x;
    if (tid < 64)       a_lds[0][tid] = a_self[h * FH_ + tid];
    else if (tid < 128) a_lds[1][tid - 64] = a_neigh[h * FH_ + tid - 64];
    __syncthreads();

    const int wave = tid >> 6, lane = tid & 63;
    const int m = lane & 15, q = lane >> 4;
    const int nl = wave * 16 + m;               // local column 0..63
    const int n = nb * 64 + nl;                 // B-frag column (node index)
    f32x4 acc[4] = {};
#pragma unroll
    for (int ks = 0; ks < 2; ++ks) {            // K = F = 64, two steps of 32
        const float* xp = X + ((size_t)(b * N_ + n)) * F_ + ks * 32 + q * 8;
        float4 x0 = *(const float4*)xp;
        float4 x1 = *(const float4*)(xp + 4);
        short8 bfrag;
        bfrag[0] = f2bf(x0.x); bfrag[1] = f2bf(x0.y);
        bfrag[2] = f2bf(x0.z); bfrag[3] = f2bf(x0.w);
        bfrag[4] = f2bf(x1.x); bfrag[5] = f2bf(x1.y);
        bfrag[6] = f2bf(x1.z); bfrag[7] = f2bf(x1.w);
#pragma unroll
        for (int ot = 0; ot < 4; ++ot) {        // 64 output features = 4 row tiles
            short8 afrag = *(const short8*)(WT + ((size_t)(h * FH_ + ot * 16 + m)) * F_ + ks * 32 + q * 8);
            acc[ot] = __builtin_amdgcn_mfma_f32_16x16x32_bf16(afrag, bfrag, acc[ot], 0, 0, 0);
        }
    }
    float ssv = 0.f, snv = 0.f;
#pragma unroll
    for (int ot = 0; ot < 4; ++ot) {
#pragma unroll
        for (int r = 0; r < 4; ++r) {
            int orow = ot * 16 + q * 4 + r;     // C: row=(lane>>4)*4+r, col=lane&15
            float v = acc[ot][r];
            c_lds[orow * 72 + nl] = __float2bfloat16(v);
            ssv += v * a_lds[0][orow];
            snv += v * a_lds[1][orow];
        }
    }
    // reduce over the 4 q-groups that share column n
    ssv += __shfl_xor(ssv, 16); ssv += __shfl_xor(ssv, 32);
    snv += __shfl_xor(snv, 16); snv += __shfl_xor(snv, 32);
    __syncthreads();
    {   // coalesced featsT store: thread t -> feature o = t>>2, 16-col chunk (t&3)
        int o = tid >> 2, c = (tid & 3) * 16;
        const __hip_bfloat16* src = c_lds + o * 72 + c;
        __hip_bfloat16* dst = featsT + ((size_t)(b * H_ + h) * FH_ + o) * N_ + nb * 64 + c;
        *(uint4*)dst       = *(const uint4*)src;        // 8 bf16
        *(uint4*)(dst + 8) = *(const uint4*)(src + 8);  // 8 bf16
    }
    if (lane < 16) {
        ss[((size_t)(b * H_ + h)) * N_ + n] = ssv * LOG2E;
        sn[((size_t)(b * H_ + h)) * N_ + n] = snv * LOG2E;
    }
}

// ---------------- K3: fused mask+softmax(no-max)+PV MFMA + epilogue ----------------
// grid (N/32, B); block = 4 waves = 4 heads, same 32 rows (A-tile shared across heads).
// exp(leaky(ss_i+sn_j)) = (hi>1 ? hi : lo), hi = 2^ss_i*2^sn_j, lo = 2^0.2ss_i*2^0.2sn_j
__global__ __launch_bounds__(256, 2) void k3_attn(const float* __restrict__ A,
                                                  const __hip_bfloat16* __restrict__ featsT,
                                                  const float* __restrict__ ss,
                                                  const float* __restrict__ sn,
                                                  const float* __restrict__ bias,
                                                  float* __restrict__ out) {
    __shared__ float e1_lds[H_ * N_];           // 32 KB: 2^sn_j per head
    __shared__ float e2_lds[H_ * N_];           // 32 KB: 2^(0.2 sn_j) per head
    const int tile = blockIdx.x, b = blockIdx.y;
    const int tid = threadIdx.x, h = tid >> 6, lane = tid & 63;
    const int m = lane & 15, q = lane >> 4;
    const int rowbase = tile * 32;

    {   // stage this head's exp tables (512 float4 slots per head)
        const float4* snrow = (const float4*)(sn + ((size_t)(b * H_ + h)) * N_);
        float4* e1v = (float4*)(e1_lds + h * N_);
        float4* e2v = (float4*)(e2_lds + h * N_);
#pragma unroll
        for (int i = 0; i < 8; ++i) {
            int idx = lane + i * 64;
            float4 v = snrow[idx];
            float4 u1, u2;
            u1.x = exp2f(v.x); u1.y = exp2f(v.y); u1.z = exp2f(v.z); u1.w = exp2f(v.w);
            u2.x = exp2f(0.2f * v.x); u2.y = exp2f(0.2f * v.y);
            u2.z = exp2f(0.2f * v.z); u2.w = exp2f(0.2f * v.w);
            e1v[idx] = u1; e2v[idx] = u2;
        }
    }
    const float ss0 = ss[((size_t)(b * H_ + h)) * N_ + rowbase + m];
    const float ss1 = ss[((size_t)(b * H_ + h)) * N_ + rowbase + 16 + m];
    const float e1i0 = exp2f(ss0), e2i0 = exp2f(0.2f * ss0);
    const float e1i1 = exp2f(ss1), e2i1 = exp2f(0.2f * ss1);
    __syncthreads();

    const float* arow0 = A + ((size_t)(b * N_ + rowbase + m)) * N_ + q * 8;
    const float* arow1 = arow0 + (size_t)16 * N_;
    const __hip_bfloat16* fb = featsT + (((size_t)(b * H_ + h)) * FH_ + m) * N_ + q * 8;
    const float* pe1 = e1_lds + h * N_ + q * 8;
    const float* pe2 = e2_lds + h * N_ + q * 8;

    f32x4 acc[2][4] = {};
    f32x4 accl[2] = {};
    short8 ones;
#pragma unroll
    for (int s = 0; s < 8; ++s) ones[s] = (short)0x3F80;   // bf16 1.0

    // --- depth-1 software prefetch ---
    float4 cA00 = *(const float4*)(arow0);
    float4 cA01 = *(const float4*)(arow0 + 4);
    float4 cA10 = *(const float4*)(arow1);
    float4 cA11 = *(const float4*)(arow1 + 4);
    short8 cF0 = *(const short8*)(fb);
    short8 cF1 = *(const short8*)(fb + (size_t)16 * N_);
    short8 cF2 = *(const short8*)(fb + (size_t)32 * N_);
    short8 cF3 = *(const short8*)(fb + (size_t)48 * N_);

#pragma unroll 2
    for (int jb = 0; jb < N_; jb += 32) {
        const int jn = (jb + 32) & (N_ - 1);    // wraps to 0 on last iter (unused)
        float4 nA00 = *(const float4*)(arow0 + jn);
        float4 nA01 = *(const float4*)(arow0 + jn + 4);
        float4 nA10 = *(const float4*)(arow1 + jn);
        float4 nA11 = *(const float4*)(arow1 + jn + 4);
        short8 nF0 = *(const short8*)(fb + jn);
        short8 nF1 = *(const short8*)(fb + (size_t)16 * N_ + jn);
        short8 nF2 = *(const short8*)(fb + (size_t)32 * N_ + jn);
        short8 nF3 = *(const short8*)(fb + (size_t)48 * N_ + jn);

        float4 ev10 = *(const float4*)(pe1 + jb);
        float4 ev11 = *(const float4*)(pe1 + jb + 4);
        float4 ev20 = *(const float4*)(pe2 + jb);
        float4 ev21 = *(const float4*)(pe2 + jb + 4);
        float e1a[8] = {ev10.x, ev10.y, ev10.z, ev10.w, ev11.x, ev11.y, ev11.z, ev11.w};
        float e2a[8] = {ev20.x, ev20.y, ev20.z, ev20.w, ev21.x, ev21.y, ev21.z, ev21.w};
        float mk0[8] = {cA00.x, cA00.y, cA00.z, cA00.w, cA01.x, cA01.y, cA01.z, cA01.w};
        float mk1[8] = {cA10.x, cA10.y, cA10.z, cA10.w, cA11.x, cA11.y, cA11.z, cA11.w};
        short8 p0, p1;
#pragma unroll
        for (int s = 0; s < 8; ++s) {
            float hi0 = e1i0 * e1a[s], lo0 = e2i0 * e2a[s];
            float hi1 = e1i1 * e1a[s], lo1 = e2i1 * e2a[s];
            float v0 = (hi0 > 1.0f) ? hi0 : lo0;    // exp2(leaky(s)), sign test exact
            float v1 = (hi1 > 1.0f) ? hi1 : lo1;
            p0[s] = f2bf(mk0[s] * v0);              // adjacency mask in {0,1}
            p1[s] = f2bf(mk1[s] * v1);
        }
        acc[0][0] = __builtin_amdgcn_mfma_f32_16x16x32_bf16(p0, cF0, acc[0][0], 0, 0, 0);
        acc[1][0] = __builtin_amdgcn_mfma_f32_16x16x32_bf16(p1, cF0, acc[1][0], 0, 0, 0);
        acc[0][1] = __builtin_amdgcn_mfma_f32_16x16x32_bf16(p0, cF1, acc[0][1], 0, 0, 0);
        acc[1][1] = __builtin_amdgcn_mfma_f32_16x16x32_bf16(p1, cF1, acc[1][1], 0, 0, 0);
        acc[0][2] = __builtin_amdgcn_mfma_f32_16x16x32_bf16(p0, cF2, acc[0][2], 0, 0, 0);
        acc[1][2] = __builtin_amdgcn_mfma_f32_16x16x32_bf16(p1, cF2, acc[1][2], 0, 0, 0);
        acc[0][3] = __builtin_amdgcn_mfma_f32_16x16x32_bf16(p0, cF3, acc[0][3], 0, 0, 0);
        acc[1][3] = __builtin_amdgcn_mfma_f32_16x16x32_bf16(p1, cF3, acc[1][3], 0, 0, 0);
        accl[0] = __builtin_amdgcn_mfma_f32_16x16x32_bf16(p0, ones, accl[0], 0, 0, 0);
        accl[1] = __builtin_amdgcn_mfma_f32_16x16x32_bf16(p1, ones, accl[1], 0, 0, 0);

        cA00 = nA00; cA01 = nA01; cA10 = nA10; cA11 = nA11;
        cF0 = nF0; cF1 = nF1; cF2 = nF2; cF3 = nF3;
    }

    float bc[4];
#pragma unroll
    for (int ct = 0; ct < 4; ++ct) bc[ct] = bias[h * FH_ + ct * 16 + m];

#pragma unroll
    for (int sub = 0; sub < 2; ++sub) {
#pragma unroll
        for (int r = 0; r < 4; ++r) {
            float inv = 1.0f / accl[sub][r];        // row sum (all cols identical)
            int gr = rowbase + sub * 16 + q * 4 + r;
#pragma unroll
            for (int ct = 0; ct < 4; ++ct) {
                float v = acc[sub][ct][r] * inv + bc[ct];
                out[((size_t)(b * N_) + gr) * C_ + h * FH_ + ct * 16 + m] = fmaxf(v, 0.0f);
            }
        }
    }
}

extern "C" void kernel_launch(void* const* d_in, const int* in_sizes, int n_in,
                              void* d_out, int out_size, void* d_ws, size_t ws_size,
                              hipStream_t stream) {
    const float* X       = (const float*)d_in[0];
    const float* A       = (const float*)d_in[1];
    const float* W       = (const float*)d_in[2];
    const float* bias    = (const float*)d_in[3];
    const float* a_self  = (const float*)d_in[4];
    const float* a_neigh = (const float*)d_in[5];
    float* out = (float*)d_out;   // reference output dtype is float32

    char* ws = (char*)d_ws;
    __hip_bfloat16* featsT = (__hip_bfloat16*)(ws);             // 8 MB   [B][H][FH][N]
    __hip_bfloat16* WT     = (__hip_bfloat16*)(ws + 8388608);   // 32 KB  [H][FH][F]
    float* ss              = (float*)(ws + 8421376);            // 256 KB [B][H][N]
    float* sn              = (float*)(ws + 8683520);            // 256 KB [B][H][N]

    k0_wt    <<<64, 256, 0, stream>>>(W, WT);
    k1_feats <<<dim3(N_ / 64, H_, B_), 256, 0, stream>>>(X, WT, a_self, a_neigh, featsT, ss, sn);
    k3_attn  <<<dim3(N_ / 32, B_), 256, 0, stream>>>(A, featsT, ss, sn, bias, out);
}